// Round 10
// baseline (382.516 us; speedup 1.0000x reference)
//
#include <hip/hip_runtime.h>
#include <hip/hip_bf16.h>

#define S_LEN 2048
#define D_MODEL 1024
#define NH 16
#define DH 64
#define M_TOK 4096  // B*S
#define DK 80       // K' row stride: 64 d + cos,sin + pad (cols 72..79 unused)
#define JS 2        // KV splits (fixed-max softmax -> linear combine in-kernel)

typedef __attribute__((ext_vector_type(8))) short bf16x8;
typedef __attribute__((ext_vector_type(4))) float f32x4;
typedef __attribute__((ext_vector_type(16))) float f32x16;

#define LOG2E 1.4426950408889634f

__device__ __forceinline__ unsigned short f2bf(float f) {
  unsigned u = __float_as_uint(f);
  u += 0x7FFF + ((u >> 16) & 1);  // RNE
  return (unsigned short)(u >> 16);
}

// raw v_exp_f32 (2^x). Scores bounded |x| << 126 here, so identical numerics
// to exp2f's OCML wrapper minus its range-reduction VALU ops.
__device__ __forceinline__ float fexp2(float x) {
#if __has_builtin(__builtin_amdgcn_exp2f)
  return __builtin_amdgcn_exp2f(x);
#else
  float r;
  asm("v_exp_f32 %0, %1" : "=v"(r) : "v"(x));
  return r;
#endif
}

// async 16B global->LDS (LDS dst must be wave-uniform base + lane*16)
__device__ __forceinline__ void gl16(const void* g, void* l) {
  __builtin_amdgcn_global_load_lds(
      (const __attribute__((address_space(1))) unsigned int*)g,
      (__attribute__((address_space(3))) unsigned int*)l, 16, 0, 0);
}

// in-place lane swap: a.hi-lanes <-> b.lo-lanes
__device__ __forceinline__ void pl32swap(unsigned int& a, unsigned int& b) {
  asm volatile("v_permlane32_swap_b32 %0, %1" : "+v"(a), "+v"(b));
}

__device__ __forceinline__ float block_sum(float v, float* sm) {
#pragma unroll
  for (int o = 32; o > 0; o >>= 1) v += __shfl_xor(v, o, 64);
  int w = threadIdx.x >> 6;
  __syncthreads();
  if ((threadIdx.x & 63) == 0) sm[w] = v;
  __syncthreads();
  return sm[0] + sm[1] + sm[2] + sm[3];
}

// ---------------- kernel 1: FUSED weight-cast + LayerNorm/phase ---------------
// blocks [0,4096): cast Wq|Wk|Wv|Wo to bf16 (block 0 also zeroes retire flags).
// blocks [4096,8192): LN + phase.
__global__ __launch_bounds__(256) void prep_ln_kernel(
    const float* __restrict__ Wq, const float* __restrict__ Wk,
    const float* __restrict__ Wv, const float* __restrict__ Wo,
    unsigned short* __restrict__ wbf, const float* __restrict__ x,
    const float* __restrict__ Wp, const float* __restrict__ gamma,
    const float* __restrict__ beta, unsigned short* __restrict__ xn,
    float* __restrict__ cosP, float* __restrict__ sinP,
    unsigned short* __restrict__ kk80, int* __restrict__ flags) {
  __shared__ float sm[4];
  int bid = blockIdx.x;
  int tid = threadIdx.x;
  if (bid < 4096) {
    if (bid == 0) ((int4*)flags)[tid] = make_int4(0, 0, 0, 0);  // 1024 flags
    int idx = (bid * 256 + tid) * 4;
    int wsel = idx >> 20;
    const float* s = (wsel == 0) ? Wq : (wsel == 1) ? Wk : (wsel == 2) ? Wv : Wo;
    int off = idx & 1048575;
    float4 v = *(const float4*)(s + off);
    ushort4 p;
    p.x = f2bf(v.x); p.y = f2bf(v.y); p.z = f2bf(v.z); p.w = f2bf(v.w);
    *(ushort4*)(wbf + idx) = p;
    return;
  }
  int row = bid - 4096;
  float4 v = ((const float4*)(x + (size_t)row * D_MODEL))[tid];
  float mu = block_sum(v.x + v.y + v.z + v.w, sm) * (1.0f / D_MODEL);
  float d0 = v.x - mu, d1 = v.y - mu, d2 = v.z - mu, d3 = v.w - mu;
  float var = block_sum(d0 * d0 + d1 * d1 + d2 * d2 + d3 * d3, sm) * (1.0f / D_MODEL);
  float rinv = rsqrtf(var + 1e-5f);
  float4 g = ((const float4*)gamma)[tid];
  float4 be = ((const float4*)beta)[tid];
  float n0 = d0 * rinv * g.x + be.x;
  float n1 = d1 * rinv * g.y + be.y;
  float n2 = d2 * rinv * g.z + be.z;
  float n3 = d3 * rinv * g.w + be.w;
  ushort4 p;
  p.x = f2bf(n0); p.y = f2bf(n1); p.z = f2bf(n2); p.w = f2bf(n3);
  ((ushort4*)(xn + (size_t)row * D_MODEL))[tid] = p;
  float4 wp = ((const float4*)Wp)[tid];
  float ph = block_sum(n0 * wp.x + n1 * wp.y + n2 * wp.z + n3 * wp.w, sm);
  if (tid == 0) {
    cosP[row] = cosf(ph);
    sinP[row] = sinf(ph);
  }
  if (tid < 16) {
    float cp = cosf(ph), sp = sinf(ph);
    unsigned int w0 = (unsigned int)f2bf(cp) | ((unsigned int)f2bf(sp) << 16);
    int b_ = row >> 11, s_ = row & (S_LEN - 1);
    *(int4*)(kk80 + ((size_t)((b_ * NH + tid) * S_LEN + s_)) * DK + 64) =
        make_int4((int)w0, 0, 0, 0);
  }
}

// ---------------- kernel 3: merged QKV GEMM (128x128, BK=64, XCD-swizzled) ----
// QK [0,512): m-panel (xn token tile) clustered per XCD (m&7 = XCD under %8).
// V [512,768): n-panel (xn token tile) clustered per XCD (n&7 = XCD).
__global__ __launch_bounds__(256, 3) void qkv_gemm_kernel(
    const unsigned short* __restrict__ xn, const unsigned short* __restrict__ wbf,
    unsigned short* __restrict__ q, unsigned short* __restrict__ kk80,
    unsigned short* __restrict__ vT) {
  __shared__ __align__(16) unsigned short As[128 * 64];
  __shared__ __align__(16) unsigned short Bs[128 * 64];
  int bid = blockIdx.x;
  bool vmode = bid >= 512;
  const unsigned short* Ap;
  const unsigned short* Bp;
  int m0, n0;
  if (!vmode) {
    int xcd = bid & 7, slot = bid >> 3;       // slot in [0,64)
    int n = slot & 15, mh = slot >> 4;        // mh in [0,4)
    int m = (mh << 3) | xcd;                  // m in [0,32)
    m0 = m * 128;                             // token tile
    n0 = n * 128;                             // e tile over stacked Wq|Wk
    Ap = xn; Bp = wbf;
  } else {
    int b2 = bid - 512;
    int xcd = b2 & 7, slot = b2 >> 3;         // slot in [0,32)
    int m = slot & 7, nh = slot >> 3;         // nh in [0,4)
    int n = (nh << 3) | xcd;                  // n in [0,32)
    m0 = m * 128;                             // Wv row tile (e)
    n0 = n * 128;                             // token tile
    Ap = wbf + 2 * D_MODEL * D_MODEL; Bp = xn;
  }
  int tid = threadIdx.x;
  int wave = tid >> 6, lane = tid & 63, quad = lane >> 4, l15 = lane & 15;
  int wm = (wave & 1) * 64, wn = (wave >> 1) * 64;
  f32x4 acc[4][4];
#pragma unroll
  for (int r = 0; r < 4; ++r)
#pragma unroll
    for (int c = 0; c < 4; ++c) acc[r][c] = (f32x4){0.f, 0.f, 0.f, 0.f};

  for (int k0 = 0; k0 < D_MODEL; k0 += 64) {
    __syncthreads();
#pragma unroll
    for (int t = 0; t < 4; ++t) {
      int c = t * 256 + tid;
      int r = c >> 3, p = c & 7;
      int g = p ^ (r & 7);
      gl16(&Ap[(size_t)(m0 + r) * D_MODEL + k0 + g * 8], &As[c * 8]);
      gl16(&Bp[(size_t)(n0 + r) * D_MODEL + k0 + g * 8], &Bs[c * 8]);
    }
    __syncthreads();
    bf16x8 af[4][2], bfr[4][2];
#pragma unroll
    for (int r = 0; r < 4; ++r) {
      int R = wm + r * 16 + l15;
#pragma unroll
      for (int h = 0; h < 2; ++h)
        af[r][h] = *(const bf16x8*)&As[R * 64 + ((h * 4 + quad) ^ (R & 7)) * 8];
    }
#pragma unroll
    for (int c = 0; c < 4; ++c) {
      int R = wn + c * 16 + l15;
#pragma unroll
      for (int h = 0; h < 2; ++h)
        bfr[c][h] = *(const bf16x8*)&Bs[R * 64 + ((h * 4 + quad) ^ (R & 7)) * 8];
    }
#pragma unroll
    for (int h = 0; h < 2; ++h)
#pragma unroll
      for (int r = 0; r < 4; ++r)
#pragma unroll
        for (int c = 0; c < 4; ++c)
          acc[r][c] = __builtin_amdgcn_mfma_f32_16x16x32_bf16(af[r][h], bfr[c][h], acc[r][c], 0, 0, 0);
  }
#pragma unroll
  for (int r = 0; r < 4; ++r) {
#pragma unroll
    for (int c = 0; c < 4; ++c) {
#pragma unroll
      for (int rr = 0; rr < 4; ++rr) {
        if (vmode) {
          int e = m0 + wm + r * 16 + quad * 4 + rr;
          int tok = n0 + wn + c * 16 + l15;
          int hh = e >> 6, d = e & 63;
          int bb = tok >> 11, ss = tok & (S_LEN - 1);
          vT[(((size_t)(bb * NH + hh)) * DH + d) * S_LEN + ss] = f2bf(acc[r][c][rr]);
        } else {
          int tok = m0 + wm + r * 16 + quad * 4 + rr;
          int n = n0 + wn + c * 16 + l15;
          int e = n & 1023;
          int hh = e >> 6, d = e & 63;
          int bb = tok >> 11, ss = tok & (S_LEN - 1);
          if ((n0 >> 10) == 0) {
            q[(((size_t)(bb * NH + hh)) * S_LEN + ss) * DH + d] =
                f2bf(acc[r][c][rr] * (0.125f * LOG2E));
          } else {
            kk80[(((size_t)(bb * NH + hh)) * S_LEN + ss) * DK + d] = f2bf(acc[r][c][rr]);
          }
        }
      }
    }
  }
}

// ---------------- kernel 4: flash attention + FUSED split-combine -------------
// R9 structure (XCD group swizzle, raw v_exp_f32, 8 blocks/CU). New: the
// combine kernel is folded in via a retire counter: both js-blocks of a
// (qt,bh) pair store partials + threadfence + atomicAdd(flag); the second
// finisher reads its partner's partials (L2-local: same XCD since g&7 is
// js-independent), applies gate/normalize, writes outw + per-pair energy.
__global__ __launch_bounds__(128, 4) void attn_kernel(
    const unsigned short* __restrict__ q, const unsigned short* __restrict__ kk80,
    const unsigned short* __restrict__ vT, const float* __restrict__ cosP,
    const float* __restrict__ sinP, const float* __restrict__ carrier,
    const float* __restrict__ lamp, float* __restrict__ Opart,
    float* __restrict__ lpart, unsigned short* __restrict__ outw,
    float* __restrict__ earray, int* __restrict__ flags) {
  __shared__ __align__(16) unsigned short Ks[64 * 72];   // natural, 9 chunks/row
  __shared__ __align__(16) unsigned short Vs[512 * 8];   // Vs[d][j], XOR-swizzled
  __shared__ float Lr[2][32];
  __shared__ float er[4];   // [0]=flag broadcast, [2],[3]=per-wave esum
  int bid = blockIdx.x;              // swizzled decode
  int slot = bid >> 3;
  int g = ((slot >> 5) << 3) | (bid & 7);  // group = h + 16*(b + 2*js)
  int qt = slot & 31;
  int h = g & 15;
  int b = (g >> 4) & 1;
  int js = g >> 5;
  int bh = b * NH + h;
  int tid = threadIdx.x, wave = tid >> 6, lane = tid & 63;
  int half = lane >> 5, l31 = lane & 31;

  const unsigned short* kb = kk80 + (size_t)bh * S_LEN * DK;
  const unsigned short* vb = vT + (size_t)bh * DH * S_LEN;
  int qrow = qt * 64 + wave * 32 + l31;

  // Q fragments: B[n=i][k], d-blocks 0..3 from global, block 4 = phase cols
  bf16x8 bQ[5];
  {
    const unsigned short* qp = q + ((size_t)bh * S_LEN + qrow) * DH;
#pragma unroll
    for (int db = 0; db < 4; ++db)
      bQ[db] = *(const bf16x8*)(qp + db * 16 + half * 8);
    bf16x8 z8 = {0, 0, 0, 0, 0, 0, 0, 0};
    if (half == 0) {
      float hl2 = 0.5f * lamp[0] * LOG2E;
      z8[0] = (short)f2bf(hl2 * cosP[b * S_LEN + qrow]);
      z8[1] = (short)f2bf(hl2 * sinP[b * S_LEN + qrow]);
    }
    bQ[4] = z8;
  }

  // tile-invariant staging offsets (hoisted out of j-loop)
  unsigned int cc0 = tid, cc1 = tid + 128, cc2 = tid + 256, cc3 = tid + 384,
               cc4 = tid + 512;
  unsigned int kr0 = cc0 / 9u, kr1 = cc1 / 9u, kr2 = cc2 / 9u, kr3 = cc3 / 9u,
               kr4 = cc4 / 9u;
  unsigned int ko0 = kr0 * DK + (cc0 - kr0 * 9u) * 8;
  unsigned int ko1 = kr1 * DK + (cc1 - kr1 * 9u) * 8;
  unsigned int ko2 = kr2 * DK + (cc2 - kr2 * 9u) * 8;
  unsigned int ko3 = kr3 * DK + (cc3 - kr3 * 9u) * 8;
  unsigned int ko4 = kr4 * DK + (cc4 - kr4 * 9u) * 8;
  unsigned short* kl0 = (unsigned short*)Ks + cc0 * 8;
  unsigned short* kl1 = (unsigned short*)Ks + cc1 * 8;
  unsigned short* kl2 = (unsigned short*)Ks + cc2 * 8;
  unsigned short* kl3 = (unsigned short*)Ks + cc3 * 8;
  unsigned short* kl4 = (unsigned short*)Ks + cc4 * 8;
  unsigned int vr0 = cc0 >> 3, vr1 = cc1 >> 3, vr2 = cc2 >> 3, vr3 = cc3 >> 3;
  unsigned int vo0 = vr0 * S_LEN + ((cc0 & 7) ^ (vr0 & 7)) * 8;
  unsigned int vo1 = vr1 * S_LEN + ((cc1 & 7) ^ (vr1 & 7)) * 8;
  unsigned int vo2 = vr2 * S_LEN + ((cc2 & 7) ^ (vr2 & 7)) * 8;
  unsigned int vo3 = vr3 * S_LEN + ((cc3 & 7) ^ (vr3 & 7)) * 8;
  unsigned short* vl0 = (unsigned short*)Vs + cc0 * 8;
  unsigned short* vl1 = (unsigned short*)Vs + cc1 * 8;
  unsigned short* vl2 = (unsigned short*)Vs + cc2 * 8;
  unsigned short* vl3 = (unsigned short*)Vs + cc3 * 8;

  const unsigned short* kbt = kb + (size_t)(js * (S_LEN / JS)) * DK;
  const unsigned short* vbt = vb + js * (S_LEN / JS);

  f32x16 O0 = {}, O1 = {};
  float2 l2 = {0.f, 0.f};

  for (int jt = 0; jt < S_LEN / (64 * JS); ++jt) {
    __syncthreads();
    gl16(kbt + ko0, kl0);
    gl16(kbt + ko1, kl1);
    gl16(kbt + ko2, kl2);
    gl16(kbt + ko3, kl3);
    if (tid < 64) gl16(kbt + ko4, kl4);
    gl16(vbt + vo0, vl0);
    gl16(vbt + vo1, vl1);
    gl16(vbt + vo2, vl2);
    gl16(vbt + vo3, vl3);
    kbt += 64 * DK;
    vbt += 64;
    __syncthreads();

    // S^T: A = K' (m=j), B = Q' (n=i); 2 j-subtiles x 5 d-blocks
    f32x16 Sf[2];
#pragma unroll
    for (int sj = 0; sj < 2; ++sj) {
      Sf[sj] = (f32x16){};
      int r = sj * 32 + l31;
      __builtin_amdgcn_s_setprio(1);
#pragma unroll
      for (int db = 0; db < 5; ++db) {
        int p = (db < 4) ? (db * 2 + half) : 8;  // db=4,half=1: don't-care (B zero)
        bf16x8 aK = *(const bf16x8*)((const unsigned short*)Ks + (r * 9 + p) * 8);
        Sf[sj] = __builtin_amdgcn_mfma_f32_32x32x16_bf16(aK, bQ[db], Sf[sj], 0, 0, 0);
      }
      __builtin_amdgcn_s_setprio(0);
    }

    // softmax (raw v_exp_f32) + P->A-frag in-register, then PV
#pragma unroll
    for (int sj = 0; sj < 2; ++sj) {
      unsigned int w[8];
#pragma unroll
      for (int rr = 0; rr < 8; ++rr) {
        float e0 = fexp2(Sf[sj][rr * 2 + 0]);
        float e1 = fexp2(Sf[sj][rr * 2 + 1]);
        l2.x += e0;
        l2.y += e1;
        __hip_bfloat162 pk2 = __float22bfloat162_rn(float2{e0, e1});
        w[rr] = *(unsigned int*)&pk2;
      }
#pragma unroll
      for (int u = 0; u < 2; ++u) {
        unsigned int a0 = w[u * 4 + 0], a1 = w[u * 4 + 1];
        unsigned int b0 = w[u * 4 + 2], b1 = w[u * 4 + 3];
        pl32swap(a0, b0);
        pl32swap(a1, b1);
        union { unsigned int u4[4]; bf16x8 v; } cvt;
        cvt.u4[0] = a0; cvt.u4[1] = a1; cvt.u4[2] = b0; cvt.u4[3] = b1;
        int jb = sj * 2 + u;
        __builtin_amdgcn_s_setprio(1);
        {
          int rv = l31;
          int p = (jb * 2 + half) ^ (rv & 7);
          bf16x8 bV = *(const bf16x8*)((const unsigned short*)Vs + (rv * 8 + p) * 8);
          O0 = __builtin_amdgcn_mfma_f32_32x32x16_bf16(cvt.v, bV, O0, 0, 0, 0);
        }
        {
          int rv = 32 + l31;
          int p = (jb * 2 + half) ^ (rv & 7);
          bf16x8 bV = *(const bf16x8*)((const unsigned short*)Vs + (rv * 8 + p) * 8);
          O1 = __builtin_amdgcn_mfma_f32_32x32x16_bf16(cvt.v, bV, O1, 0, 0, 0);
        }
        __builtin_amdgcn_s_setprio(0);
      }
    }
  }

  // ---- epilogue: store partials, retire-count, second finisher combines ----
  float l_i = l2.x + l2.y;
  l_i += __shfl_xor(l_i, 32, 64);
  Lr[wave][l31] = l_i;  // row-sum for local q-row wave*32+l31
  size_t obase = (size_t)(js * 2 * NH + bh) * S_LEN;  // [js][bh] plane
#pragma unroll
  for (int reg = 0; reg < 16; ++reg) {
    int ir = (reg & 3) + 8 * (reg >> 2) + 4 * half;
    int srow = qt * 64 + wave * 32 + ir;
    Opart[(obase + srow) * DH + l31] = O0[reg];
    Opart[(obase + srow) * DH + 32 + l31] = O1[reg];
  }
  if (half == 0) lpart[obase + qt * 64 + wave * 32 + l31] = l_i;
  __threadfence();          // release: partials visible device-wide
  __syncthreads();          // all threads' stores+fences done; Lr visible
  int pair = bh * 32 + qt;
  if (tid == 0) er[0] = (float)atomicAdd(&flags[pair], 1);
  __syncthreads();
  if (er[0] < 0.5f) return;  // first finisher: partner will combine
  __threadfence();           // acquire: partner's partials now readable

  size_t pbase = (size_t)((1 - js) * 2 * NH + bh) * S_LEN;  // partner plane
  float ch = cosf(carrier[h]), sh = sinf(carrier[h]);
  float esum = 0.f;
#pragma unroll
  for (int reg = 0; reg < 16; ++reg) {
    int ir = (reg & 3) + 8 * (reg >> 2) + 4 * half;
    int srow = qt * 64 + wave * 32 + ir;
    float lT = Lr[wave][ir] + lpart[pbase + srow];
    float cp = cosP[b * S_LEN + srow], sp = sinP[b * S_LEN + srow];
    float gate = 0.5f + 0.5f * (cp * ch + sp * sh);
    float gl = gate / lT;
    float v0 = (O0[reg] + Opart[(pbase + srow) * DH + l31]) * gl;
    float v1 = (O1[reg] + Opart[(pbase + srow) * DH + 32 + l31]) * gl;
    esum += fabsf(v0) + fabsf(v1);
    size_t tok = (size_t)b * S_LEN + srow;
    outw[tok * D_MODEL + h * DH + l31] = f2bf(v0);
    outw[tok * D_MODEL + h * DH + 32 + l31] = f2bf(v1);
  }
#pragma unroll
  for (int off = 32; off > 0; off >>= 1) esum += __shfl_xor(esum, off, 64);
  if (lane == 0) er[2 + wave] = esum;
  __syncthreads();
  if (tid == 0) earray[pair] = er[2] + er[3];  // per-pair partial, no atomic
}

// ---------------- kernel 5: output projection + residual (128x64, 2 blk/CU) --
// 1-D swizzled grid: 16 n-blocks sharing an outw token-panel cluster per XCD.
// Block 0 folds the 1024-entry energy reduction (plain store).
__global__ __launch_bounds__(256, 3) void out_gemm_kernel(
    const unsigned short* __restrict__ A, const unsigned short* __restrict__ Wo,
    const float* __restrict__ x, const float* __restrict__ earray,
    float* __restrict__ y, float* __restrict__ energy) {
  __shared__ __align__(16) unsigned short As[128 * 64];
  __shared__ __align__(16) unsigned short Bs[64 * 64];
  __shared__ float sm[4];
  int tid = threadIdx.x;
  int bid = blockIdx.x;  // 512 blocks
  if (bid == 0) {
    float v = earray[tid] + earray[tid + 256] + earray[tid + 512] + earray[tid + 768];
    float tot = block_sum(v, sm);
    if (tid == 0) *energy = tot;
  }
  int xcd = bid & 7, slot = bid >> 3;   // slot in [0,64)
  int n = slot & 15, mh = slot >> 4;    // mh in [0,4)
  int m = (mh << 3) | xcd;              // m in [0,32)
  int m0 = m * 128, n0 = n * 64;
  int wave = tid >> 6, lane = tid & 63, quad = lane >> 4, l15 = lane & 15;
  int wm = (wave & 1) * 64, wn = (wave >> 1) * 32;
  f32x4 acc[4][2];
#pragma unroll
  for (int r = 0; r < 4; ++r)
#pragma unroll
    for (int c = 0; c < 2; ++c) acc[r][c] = (f32x4){0.f, 0.f, 0.f, 0.f};

  for (int k0 = 0; k0 < D_MODEL; k0 += 64) {
    __syncthreads();
#pragma unroll
    for (int t = 0; t < 4; ++t) {
      int c = t * 256 + tid;
      int r = c >> 3, p = c & 7;
      int qc = p ^ (r & 7);
      gl16(&A[(size_t)(m0 + r) * D_MODEL + k0 + qc * 8], &As[c * 8]);
    }
#pragma unroll
    for (int t = 0; t < 2; ++t) {
      int c = t * 256 + tid;
      int r = c >> 3, p = c & 7;
      int qc = p ^ (r & 7);
      gl16(&Wo[(size_t)(n0 + r) * D_MODEL + k0 + qc * 8], &Bs[c * 8]);
    }
    __syncthreads();
    bf16x8 af[4][2], bfr[2][2];
#pragma unroll
    for (int r = 0; r < 4; ++r) {
      int R = wm + r * 16 + l15;
#pragma unroll
      for (int h = 0; h < 2; ++h)
        af[r][h] = *(const bf16x8*)&As[R * 64 + ((h * 4 + quad) ^ (R & 7)) * 8];
    }
#pragma unroll
    for (int c = 0; c < 2; ++c) {
      int R = wn + c * 16 + l15;
#pragma unroll
      for (int h = 0; h < 2; ++h)
        bfr[c][h] = *(const bf16x8*)&Bs[R * 64 + ((h * 4 + quad) ^ (R & 7)) * 8];
    }
#pragma unroll
    for (int h = 0; h < 2; ++h)
#pragma unroll
      for (int r = 0; r < 4; ++r)
#pragma unroll
        for (int c = 0; c < 2; ++c)
          acc[r][c] = __builtin_amdgcn_mfma_f32_16x16x32_bf16(af[r][h], bfr[c][h], acc[r][c], 0, 0, 0);
  }
#pragma unroll
  for (int r = 0; r < 4; ++r) {
#pragma unroll
    for (int c = 0; c < 2; ++c) {
      int dcol = n0 + wn + c * 16 + l15;
#pragma unroll
      for (int rr = 0; rr < 4; ++rr) {
        int tok = m0 + wm + r * 16 + quad * 4 + rr;
        size_t idx = (size_t)tok * D_MODEL + dcol;
        y[idx] = x[idx] + acc[r][c][rr];
      }
    }
  }
}

extern "C" void kernel_launch(void* const* d_in, const int* in_sizes, int n_in,
                              void* d_out, int out_size, void* d_ws, size_t ws_size,
                              hipStream_t stream) {
  const float* x = (const float*)d_in[0];
  const float* Wq = (const float*)d_in[1];
  const float* Wk = (const float*)d_in[2];
  const float* Wv = (const float*)d_in[3];
  const float* Wo = (const float*)d_in[4];
  const float* Wp = (const float*)d_in[5];
  const float* gamma = (const float*)d_in[6];
  const float* beta = (const float*)d_in[7];
  const float* carrier = (const float*)d_in[8];
  const float* lam = (const float*)d_in[9];

  char* ws = (char*)d_ws;
  const size_t MB = 1024 * 1024;
  unsigned short* wbf = (unsigned short*)(ws);            // 8 MB (Wq|Wk|Wv|Wo)
  unsigned short* xn = (unsigned short*)(ws + 8 * MB);    // 8 MB (aliased: outw)
  unsigned short* qq = (unsigned short*)(ws + 16 * MB);   // 8 MB (bh,S,64)
  unsigned short* kk80 = (unsigned short*)(ws + 24 * MB); // 10 MB (bh,S,80)
  unsigned short* vT = (unsigned short*)(ws + 34 * MB);   // 8 MB (bh,64,S)
  float* cosP = (float*)(ws + 42 * MB);                   // 16 KB
  float* sinP = (float*)(ws + 42 * MB + 16 * 1024);       // 16 KB
  float* Opart = (float*)(ws + 43 * MB);                  // 32 MB ([js][bh][s][d] f32)
  float* lpart = (float*)(ws + 75 * MB);                  // 512 KB ([js][bh][s])
  float* earray = (float*)(ws + 76 * MB);                 // 4 KB (per-pair energy)
  int* flags = (int*)(ws + 76 * MB + 8 * 1024);           // 4 KB (retire counters)
  unsigned short* outw = xn;  // attn runs after qkv consumed xn

  float* y = (float*)d_out;
  float* energy = y + (out_size - 1);

  prep_ln_kernel<<<8192, 256, 0, stream>>>(Wq, Wk, Wv, Wo, wbf, x, Wp, gamma,
                                           beta, xn, cosP, sinP, kk80, flags);
  qkv_gemm_kernel<<<768, 256, 0, stream>>>(xn, wbf, qq, kk80, vT);
  attn_kernel<<<2048, 128, 0, stream>>>(qq, kk80, vT, cosP, sinP, carrier, lam,
                                        Opart, lpart, outw, earray, flags);
  out_gemm_kernel<<<512, 256, 0, stream>>>(outw, wbf + 3 * D_MODEL * D_MODEL,
                                           x, earray, y, energy);
}

// Round 11
// 211.649 us; speedup vs baseline: 1.8073x; 1.8073x over previous
//
#include <hip/hip_runtime.h>
#include <hip/hip_bf16.h>

#define S_LEN 2048
#define D_MODEL 1024
#define NH 16
#define DH 64
#define M_TOK 4096  // B*S
#define DK 80       // K' row stride: 64 d + cos,sin + pad (cols 72..79 unused)
#define JS 2        // KV splits (fixed-max softmax -> linear combine kernel)

typedef __attribute__((ext_vector_type(8))) short bf16x8;
typedef __attribute__((ext_vector_type(4))) float f32x4;
typedef __attribute__((ext_vector_type(16))) float f32x16;

#define LOG2E 1.4426950408889634f

__device__ __forceinline__ unsigned short f2bf(float f) {
  unsigned u = __float_as_uint(f);
  u += 0x7FFF + ((u >> 16) & 1);  // RNE
  return (unsigned short)(u >> 16);
}

// raw v_exp_f32 (2^x). Scores bounded |x| << 126 here, so identical numerics
// to exp2f's OCML wrapper minus its range-reduction VALU ops.
__device__ __forceinline__ float fexp2(float x) {
#if __has_builtin(__builtin_amdgcn_exp2f)
  return __builtin_amdgcn_exp2f(x);
#else
  float r;
  asm("v_exp_f32 %0, %1" : "=v"(r) : "v"(x));
  return r;
#endif
}

// async 16B global->LDS (LDS dst must be wave-uniform base + lane*16)
__device__ __forceinline__ void gl16(const void* g, void* l) {
  __builtin_amdgcn_global_load_lds(
      (const __attribute__((address_space(1))) unsigned int*)g,
      (__attribute__((address_space(3))) unsigned int*)l, 16, 0, 0);
}

// in-place lane swap: a.hi-lanes <-> b.lo-lanes
__device__ __forceinline__ void pl32swap(unsigned int& a, unsigned int& b) {
  asm volatile("v_permlane32_swap_b32 %0, %1" : "+v"(a), "+v"(b));
}

__device__ __forceinline__ float block_sum(float v, float* sm) {
#pragma unroll
  for (int o = 32; o > 0; o >>= 1) v += __shfl_xor(v, o, 64);
  int w = threadIdx.x >> 6;
  __syncthreads();
  if ((threadIdx.x & 63) == 0) sm[w] = v;
  __syncthreads();
  return sm[0] + sm[1] + sm[2] + sm[3];
}

// ---------------- kernel 1: FUSED weight-cast + LayerNorm/phase ---------------
// blocks [0,4096): cast Wq|Wk|Wv|Wo to bf16.  blocks [4096,8192): LN + phase.
__global__ __launch_bounds__(256) void prep_ln_kernel(
    const float* __restrict__ Wq, const float* __restrict__ Wk,
    const float* __restrict__ Wv, const float* __restrict__ Wo,
    unsigned short* __restrict__ wbf, const float* __restrict__ x,
    const float* __restrict__ Wp, const float* __restrict__ gamma,
    const float* __restrict__ beta, unsigned short* __restrict__ xn,
    float* __restrict__ cosP, float* __restrict__ sinP,
    unsigned short* __restrict__ kk80) {
  __shared__ float sm[4];
  int bid = blockIdx.x;
  int tid = threadIdx.x;
  if (bid < 4096) {
    int idx = (bid * 256 + tid) * 4;
    int wsel = idx >> 20;
    const float* s = (wsel == 0) ? Wq : (wsel == 1) ? Wk : (wsel == 2) ? Wv : Wo;
    int off = idx & 1048575;
    float4 v = *(const float4*)(s + off);
    ushort4 p;
    p.x = f2bf(v.x); p.y = f2bf(v.y); p.z = f2bf(v.z); p.w = f2bf(v.w);
    *(ushort4*)(wbf + idx) = p;
    return;
  }
  int row = bid - 4096;
  float4 v = ((const float4*)(x + (size_t)row * D_MODEL))[tid];
  float mu = block_sum(v.x + v.y + v.z + v.w, sm) * (1.0f / D_MODEL);
  float d0 = v.x - mu, d1 = v.y - mu, d2 = v.z - mu, d3 = v.w - mu;
  float var = block_sum(d0 * d0 + d1 * d1 + d2 * d2 + d3 * d3, sm) * (1.0f / D_MODEL);
  float rinv = rsqrtf(var + 1e-5f);
  float4 g = ((const float4*)gamma)[tid];
  float4 be = ((const float4*)beta)[tid];
  float n0 = d0 * rinv * g.x + be.x;
  float n1 = d1 * rinv * g.y + be.y;
  float n2 = d2 * rinv * g.z + be.z;
  float n3 = d3 * rinv * g.w + be.w;
  ushort4 p;
  p.x = f2bf(n0); p.y = f2bf(n1); p.z = f2bf(n2); p.w = f2bf(n3);
  ((ushort4*)(xn + (size_t)row * D_MODEL))[tid] = p;
  float4 wp = ((const float4*)Wp)[tid];
  float ph = block_sum(n0 * wp.x + n1 * wp.y + n2 * wp.z + n3 * wp.w, sm);
  if (tid == 0) {
    cosP[row] = cosf(ph);
    sinP[row] = sinf(ph);
  }
  if (tid < 16) {
    float cp = cosf(ph), sp = sinf(ph);
    unsigned int w0 = (unsigned int)f2bf(cp) | ((unsigned int)f2bf(sp) << 16);
    int b_ = row >> 11, s_ = row & (S_LEN - 1);
    *(int4*)(kk80 + ((size_t)((b_ * NH + tid) * S_LEN + s_)) * DK + 64) =
        make_int4((int)w0, 0, 0, 0);
  }
}

// ---------------- kernel 3: merged QKV GEMM (128x128, BK=64, XCD-swizzled) ----
// QK [0,512): m-panel (xn token tile) clustered per XCD (m&7 = XCD under %8).
// V [512,768): n-panel (xn token tile) clustered per XCD (n&7 = XCD).
__global__ __launch_bounds__(256, 3) void qkv_gemm_kernel(
    const unsigned short* __restrict__ xn, const unsigned short* __restrict__ wbf,
    unsigned short* __restrict__ q, unsigned short* __restrict__ kk80,
    unsigned short* __restrict__ vT) {
  __shared__ __align__(16) unsigned short As[128 * 64];
  __shared__ __align__(16) unsigned short Bs[128 * 64];
  int bid = blockIdx.x;
  bool vmode = bid >= 512;
  const unsigned short* Ap;
  const unsigned short* Bp;
  int m0, n0;
  if (!vmode) {
    int xcd = bid & 7, slot = bid >> 3;       // slot in [0,64)
    int n = slot & 15, mh = slot >> 4;        // mh in [0,4)
    int m = (mh << 3) | xcd;                  // m in [0,32)
    m0 = m * 128;                             // token tile
    n0 = n * 128;                             // e tile over stacked Wq|Wk
    Ap = xn; Bp = wbf;
  } else {
    int b2 = bid - 512;
    int xcd = b2 & 7, slot = b2 >> 3;         // slot in [0,32)
    int m = slot & 7, nh = slot >> 3;         // nh in [0,4)
    int n = (nh << 3) | xcd;                  // n in [0,32)
    m0 = m * 128;                             // Wv row tile (e)
    n0 = n * 128;                             // token tile
    Ap = wbf + 2 * D_MODEL * D_MODEL; Bp = xn;
  }
  int tid = threadIdx.x;
  int wave = tid >> 6, lane = tid & 63, quad = lane >> 4, l15 = lane & 15;
  int wm = (wave & 1) * 64, wn = (wave >> 1) * 64;
  f32x4 acc[4][4];
#pragma unroll
  for (int r = 0; r < 4; ++r)
#pragma unroll
    for (int c = 0; c < 4; ++c) acc[r][c] = (f32x4){0.f, 0.f, 0.f, 0.f};

  for (int k0 = 0; k0 < D_MODEL; k0 += 64) {
    __syncthreads();
#pragma unroll
    for (int t = 0; t < 4; ++t) {
      int c = t * 256 + tid;
      int r = c >> 3, p = c & 7;
      int g = p ^ (r & 7);
      gl16(&Ap[(size_t)(m0 + r) * D_MODEL + k0 + g * 8], &As[c * 8]);
      gl16(&Bp[(size_t)(n0 + r) * D_MODEL + k0 + g * 8], &Bs[c * 8]);
    }
    __syncthreads();
    bf16x8 af[4][2], bfr[4][2];
#pragma unroll
    for (int r = 0; r < 4; ++r) {
      int R = wm + r * 16 + l15;
#pragma unroll
      for (int h = 0; h < 2; ++h)
        af[r][h] = *(const bf16x8*)&As[R * 64 + ((h * 4 + quad) ^ (R & 7)) * 8];
    }
#pragma unroll
    for (int c = 0; c < 4; ++c) {
      int R = wn + c * 16 + l15;
#pragma unroll
      for (int h = 0; h < 2; ++h)
        bfr[c][h] = *(const bf16x8*)&Bs[R * 64 + ((h * 4 + quad) ^ (R & 7)) * 8];
    }
#pragma unroll
    for (int h = 0; h < 2; ++h)
#pragma unroll
      for (int r = 0; r < 4; ++r)
#pragma unroll
        for (int c = 0; c < 4; ++c)
          acc[r][c] = __builtin_amdgcn_mfma_f32_16x16x32_bf16(af[r][h], bfr[c][h], acc[r][c], 0, 0, 0);
  }
#pragma unroll
  for (int r = 0; r < 4; ++r) {
#pragma unroll
    for (int c = 0; c < 4; ++c) {
#pragma unroll
      for (int rr = 0; rr < 4; ++rr) {
        if (vmode) {
          int e = m0 + wm + r * 16 + quad * 4 + rr;
          int tok = n0 + wn + c * 16 + l15;
          int hh = e >> 6, d = e & 63;
          int bb = tok >> 11, ss = tok & (S_LEN - 1);
          vT[(((size_t)(bb * NH + hh)) * DH + d) * S_LEN + ss] = f2bf(acc[r][c][rr]);
        } else {
          int tok = m0 + wm + r * 16 + quad * 4 + rr;
          int n = n0 + wn + c * 16 + l15;
          int e = n & 1023;
          int hh = e >> 6, d = e & 63;
          int bb = tok >> 11, ss = tok & (S_LEN - 1);
          if ((n0 >> 10) == 0) {
            q[(((size_t)(bb * NH + hh)) * S_LEN + ss) * DH + d] =
                f2bf(acc[r][c][rr] * (0.125f * LOG2E));
          } else {
            kk80[(((size_t)(bb * NH + hh)) * S_LEN + ss) * DK + d] = f2bf(acc[r][c][rr]);
          }
        }
      }
    }
  }
}

// ---------------- kernel 4: flash attention (R9 proven: swizzle + v_exp) ------
// R10 lesson: NO device-scope fences in-kernel (threadfence -> L2 writeback,
// 59->250 us). Partials go to workspace; combine is a separate launch (the
// launch boundary is the cheap fence).
__global__ __launch_bounds__(128, 4) void attn_kernel(
    const unsigned short* __restrict__ q, const unsigned short* __restrict__ kk80,
    const unsigned short* __restrict__ vT, const float* __restrict__ cosP,
    const float* __restrict__ sinP, const float* __restrict__ lamp,
    float* __restrict__ Opart, float* __restrict__ lpart) {
  __shared__ __align__(16) unsigned short Ks[64 * 72];   // natural, 9 chunks/row
  __shared__ __align__(16) unsigned short Vs[512 * 8];   // Vs[d][j], XOR-swizzled
  int bid = blockIdx.x;              // swizzled decode
  int slot = bid >> 3;
  int g = ((slot >> 5) << 3) | (bid & 7);  // group = h + 16*(b + 2*js)
  int qt = slot & 31;
  int h = g & 15;
  int b = (g >> 4) & 1;
  int js = g >> 5;
  int bh = b * NH + h;
  int tid = threadIdx.x, wave = tid >> 6, lane = tid & 63;
  int half = lane >> 5, l31 = lane & 31;

  const unsigned short* kb = kk80 + (size_t)bh * S_LEN * DK;
  const unsigned short* vb = vT + (size_t)bh * DH * S_LEN;
  int qrow = qt * 64 + wave * 32 + l31;

  // Q fragments: B[n=i][k], d-blocks 0..3 from global, block 4 = phase cols
  bf16x8 bQ[5];
  {
    const unsigned short* qp = q + ((size_t)bh * S_LEN + qrow) * DH;
#pragma unroll
    for (int db = 0; db < 4; ++db)
      bQ[db] = *(const bf16x8*)(qp + db * 16 + half * 8);
    bf16x8 z8 = {0, 0, 0, 0, 0, 0, 0, 0};
    if (half == 0) {
      float hl2 = 0.5f * lamp[0] * LOG2E;
      z8[0] = (short)f2bf(hl2 * cosP[b * S_LEN + qrow]);
      z8[1] = (short)f2bf(hl2 * sinP[b * S_LEN + qrow]);
    }
    bQ[4] = z8;
  }

  // tile-invariant staging offsets (hoisted out of j-loop)
  unsigned int cc0 = tid, cc1 = tid + 128, cc2 = tid + 256, cc3 = tid + 384,
               cc4 = tid + 512;
  unsigned int kr0 = cc0 / 9u, kr1 = cc1 / 9u, kr2 = cc2 / 9u, kr3 = cc3 / 9u,
               kr4 = cc4 / 9u;
  unsigned int ko0 = kr0 * DK + (cc0 - kr0 * 9u) * 8;
  unsigned int ko1 = kr1 * DK + (cc1 - kr1 * 9u) * 8;
  unsigned int ko2 = kr2 * DK + (cc2 - kr2 * 9u) * 8;
  unsigned int ko3 = kr3 * DK + (cc3 - kr3 * 9u) * 8;
  unsigned int ko4 = kr4 * DK + (cc4 - kr4 * 9u) * 8;
  unsigned short* kl0 = (unsigned short*)Ks + cc0 * 8;
  unsigned short* kl1 = (unsigned short*)Ks + cc1 * 8;
  unsigned short* kl2 = (unsigned short*)Ks + cc2 * 8;
  unsigned short* kl3 = (unsigned short*)Ks + cc3 * 8;
  unsigned short* kl4 = (unsigned short*)Ks + cc4 * 8;
  unsigned int vr0 = cc0 >> 3, vr1 = cc1 >> 3, vr2 = cc2 >> 3, vr3 = cc3 >> 3;
  unsigned int vo0 = vr0 * S_LEN + ((cc0 & 7) ^ (vr0 & 7)) * 8;
  unsigned int vo1 = vr1 * S_LEN + ((cc1 & 7) ^ (vr1 & 7)) * 8;
  unsigned int vo2 = vr2 * S_LEN + ((cc2 & 7) ^ (vr2 & 7)) * 8;
  unsigned int vo3 = vr3 * S_LEN + ((cc3 & 7) ^ (vr3 & 7)) * 8;
  unsigned short* vl0 = (unsigned short*)Vs + cc0 * 8;
  unsigned short* vl1 = (unsigned short*)Vs + cc1 * 8;
  unsigned short* vl2 = (unsigned short*)Vs + cc2 * 8;
  unsigned short* vl3 = (unsigned short*)Vs + cc3 * 8;

  const unsigned short* kbt = kb + (size_t)(js * (S_LEN / JS)) * DK;
  const unsigned short* vbt = vb + js * (S_LEN / JS);

  f32x16 O0 = {}, O1 = {};
  float2 l2 = {0.f, 0.f};

  for (int jt = 0; jt < S_LEN / (64 * JS); ++jt) {
    __syncthreads();
    gl16(kbt + ko0, kl0);
    gl16(kbt + ko1, kl1);
    gl16(kbt + ko2, kl2);
    gl16(kbt + ko3, kl3);
    if (tid < 64) gl16(kbt + ko4, kl4);
    gl16(vbt + vo0, vl0);
    gl16(vbt + vo1, vl1);
    gl16(vbt + vo2, vl2);
    gl16(vbt + vo3, vl3);
    kbt += 64 * DK;
    vbt += 64;
    __syncthreads();

    // S^T: A = K' (m=j), B = Q' (n=i); 2 j-subtiles x 5 d-blocks
    f32x16 Sf[2];
#pragma unroll
    for (int sj = 0; sj < 2; ++sj) {
      Sf[sj] = (f32x16){};
      int r = sj * 32 + l31;
      __builtin_amdgcn_s_setprio(1);
#pragma unroll
      for (int db = 0; db < 5; ++db) {
        int p = (db < 4) ? (db * 2 + half) : 8;  // db=4,half=1: don't-care (B zero)
        bf16x8 aK = *(const bf16x8*)((const unsigned short*)Ks + (r * 9 + p) * 8);
        Sf[sj] = __builtin_amdgcn_mfma_f32_32x32x16_bf16(aK, bQ[db], Sf[sj], 0, 0, 0);
      }
      __builtin_amdgcn_s_setprio(0);
    }

    // softmax (raw v_exp_f32) + P->A-frag in-register, then PV
#pragma unroll
    for (int sj = 0; sj < 2; ++sj) {
      unsigned int w[8];
#pragma unroll
      for (int rr = 0; rr < 8; ++rr) {
        float e0 = fexp2(Sf[sj][rr * 2 + 0]);
        float e1 = fexp2(Sf[sj][rr * 2 + 1]);
        l2.x += e0;
        l2.y += e1;
        __hip_bfloat162 pk2 = __float22bfloat162_rn(float2{e0, e1});
        w[rr] = *(unsigned int*)&pk2;
      }
#pragma unroll
      for (int u = 0; u < 2; ++u) {
        unsigned int a0 = w[u * 4 + 0], a1 = w[u * 4 + 1];
        unsigned int b0 = w[u * 4 + 2], b1 = w[u * 4 + 3];
        pl32swap(a0, b0);
        pl32swap(a1, b1);
        union { unsigned int u4[4]; bf16x8 v; } cvt;
        cvt.u4[0] = a0; cvt.u4[1] = a1; cvt.u4[2] = b0; cvt.u4[3] = b1;
        int jb = sj * 2 + u;
        __builtin_amdgcn_s_setprio(1);
        {
          int rv = l31;
          int p = (jb * 2 + half) ^ (rv & 7);
          bf16x8 bV = *(const bf16x8*)((const unsigned short*)Vs + (rv * 8 + p) * 8);
          O0 = __builtin_amdgcn_mfma_f32_32x32x16_bf16(cvt.v, bV, O0, 0, 0, 0);
        }
        {
          int rv = 32 + l31;
          int p = (jb * 2 + half) ^ (rv & 7);
          bf16x8 bV = *(const bf16x8*)((const unsigned short*)Vs + (rv * 8 + p) * 8);
          O1 = __builtin_amdgcn_mfma_f32_32x32x16_bf16(cvt.v, bV, O1, 0, 0, 0);
        }
        __builtin_amdgcn_s_setprio(0);
      }
    }
  }

  // epilogue: complete per-row sums, store f32 partials (no gate/normalize here)
  float l_i = l2.x + l2.y;
  l_i += __shfl_xor(l_i, 32, 64);
  size_t obase = (size_t)(js * 2 * NH + bh) * S_LEN;  // [js][bh] plane
#pragma unroll
  for (int reg = 0; reg < 16; ++reg) {
    int ir = (reg & 3) + 8 * (reg >> 2) + 4 * half;
    int srow = qt * 64 + wave * 32 + ir;
    Opart[((size_t)(obase + srow)) * DH + l31] = O0[reg];
    Opart[((size_t)(obase + srow)) * DH + 32 + l31] = O1[reg];
  }
  if (half == 0) lpart[obase + qt * 64 + wave * 32 + l31] = l_i;
}

// ---------------- kernel 4b: combine splits + gate + normalize (no atomics) ---
__global__ __launch_bounds__(256) void combine_kernel(
    const float* __restrict__ Opart, const float* __restrict__ lpart,
    const float* __restrict__ cosP, const float* __restrict__ sinP,
    const float* __restrict__ carrier, unsigned short* __restrict__ outw,
    float* __restrict__ earray) {
  __shared__ float sm[4];
  int tok = blockIdx.x;  // 4096 = b*2048 + s
  int b = tok >> 11, s = tok & (S_LEN - 1);
  int t = threadIdx.x;
  int c0 = t * 4;
  int h = c0 >> 6, d0 = c0 & 63;
  int bh = b * NH + h;
  const size_t plane = (size_t)2 * NH * S_LEN;  // js stride in rows
  size_t row0 = (size_t)bh * S_LEN + s;
  float4 a0 = *(const float4*)(Opart + row0 * DH + d0);
  float4 a1 = *(const float4*)(Opart + (plane + row0) * DH + d0);
  float l = lpart[row0] + lpart[plane + row0];
  float ch = cosf(carrier[h]), sh = sinf(carrier[h]);
  float cp = cosP[tok], sp = sinP[tok];
  float gate = 0.5f + 0.5f * (cp * ch + sp * sh);
  float gl = gate / l;
  float v0 = (a0.x + a1.x) * gl, v1 = (a0.y + a1.y) * gl;
  float v2 = (a0.z + a1.z) * gl, v3 = (a0.w + a1.w) * gl;
  ushort4 p;
  p.x = f2bf(v0); p.y = f2bf(v1); p.z = f2bf(v2); p.w = f2bf(v3);
  *(ushort4*)(outw + (size_t)tok * D_MODEL + c0) = p;
  float esum = fabsf(v0) + fabsf(v1) + fabsf(v2) + fabsf(v3);
  float tot = block_sum(esum, sm);
  if (t == 0) earray[tok] = tot;  // per-block partial, no atomic
}

// ---------------- kernel 5: output projection + residual (128x64, 2 blk/CU) --
// 1-D swizzled grid: 16 n-blocks sharing an outw token-panel cluster per XCD.
// Block 0 folds the 4096-entry energy reduction (plain store).
__global__ __launch_bounds__(256, 3) void out_gemm_kernel(
    const unsigned short* __restrict__ A, const unsigned short* __restrict__ Wo,
    const float* __restrict__ x, const float* __restrict__ earray,
    float* __restrict__ y, float* __restrict__ energy) {
  __shared__ __align__(16) unsigned short As[128 * 64];
  __shared__ __align__(16) unsigned short Bs[64 * 64];
  __shared__ float sm[4];
  int tid = threadIdx.x;
  int bid = blockIdx.x;  // 512 blocks
  if (bid == 0) {
    float v = 0.f;
#pragma unroll
    for (int i = 0; i < 16; ++i) v += earray[tid + i * 256];
    float tot = block_sum(v, sm);
    if (tid == 0) *energy = tot;
  }
  int xcd = bid & 7, slot = bid >> 3;   // slot in [0,64)
  int n = slot & 15, mh = slot >> 4;    // mh in [0,4)
  int m = (mh << 3) | xcd;              // m in [0,32)
  int m0 = m * 128, n0 = n * 64;
  int wave = tid >> 6, lane = tid & 63, quad = lane >> 4, l15 = lane & 15;
  int wm = (wave & 1) * 64, wn = (wave >> 1) * 32;
  f32x4 acc[4][2];
#pragma unroll
  for (int r = 0; r < 4; ++r)
#pragma unroll
    for (int c = 0; c < 2; ++c) acc[r][c] = (f32x4){0.f, 0.f, 0.f, 0.f};

  for (int k0 = 0; k0 < D_MODEL; k0 += 64) {
    __syncthreads();
#pragma unroll
    for (int t = 0; t < 4; ++t) {
      int c = t * 256 + tid;
      int r = c >> 3, p = c & 7;
      int qc = p ^ (r & 7);
      gl16(&A[(size_t)(m0 + r) * D_MODEL + k0 + qc * 8], &As[c * 8]);
    }
#pragma unroll
    for (int t = 0; t < 2; ++t) {
      int c = t * 256 + tid;
      int r = c >> 3, p = c & 7;
      int qc = p ^ (r & 7);
      gl16(&Wo[(size_t)(n0 + r) * D_MODEL + k0 + qc * 8], &Bs[c * 8]);
    }
    __syncthreads();
    bf16x8 af[4][2], bfr[2][2];
#pragma unroll
    for (int r = 0; r < 4; ++r) {
      int R = wm + r * 16 + l15;
#pragma unroll
      for (int h = 0; h < 2; ++h)
        af[r][h] = *(const bf16x8*)&As[R * 64 + ((h * 4 + quad) ^ (R & 7)) * 8];
    }
#pragma unroll
    for (int c = 0; c < 2; ++c) {
      int R = wn + c * 16 + l15;
#pragma unroll
      for (int h = 0; h < 2; ++h)
        bfr[c][h] = *(const bf16x8*)&Bs[R * 64 + ((h * 4 + quad) ^ (R & 7)) * 8];
    }
#pragma unroll
    for (int h = 0; h < 2; ++h)
#pragma unroll
      for (int r = 0; r < 4; ++r)
#pragma unroll
        for (int c = 0; c < 2; ++c)
          acc[r][c] = __builtin_amdgcn_mfma_f32_16x16x32_bf16(af[r][h], bfr[c][h], acc[r][c], 0, 0, 0);
  }
#pragma unroll
  for (int r = 0; r < 4; ++r) {
#pragma unroll
    for (int c = 0; c < 2; ++c) {
      int dcol = n0 + wn + c * 16 + l15;
#pragma unroll
      for (int rr = 0; rr < 4; ++rr) {
        int tok = m0 + wm + r * 16 + quad * 4 + rr;
        size_t idx = (size_t)tok * D_MODEL + dcol;
        y[idx] = x[idx] + acc[r][c][rr];
      }
    }
  }
}

extern "C" void kernel_launch(void* const* d_in, const int* in_sizes, int n_in,
                              void* d_out, int out_size, void* d_ws, size_t ws_size,
                              hipStream_t stream) {
  const float* x = (const float*)d_in[0];
  const float* Wq = (const float*)d_in[1];
  const float* Wk = (const float*)d_in[2];
  const float* Wv = (const float*)d_in[3];
  const float* Wo = (const float*)d_in[4];
  const float* Wp = (const float*)d_in[5];
  const float* gamma = (const float*)d_in[6];
  const float* beta = (const float*)d_in[7];
  const float* carrier = (const float*)d_in[8];
  const float* lam = (const float*)d_in[9];

  char* ws = (char*)d_ws;
  const size_t MB = 1024 * 1024;
  unsigned short* wbf = (unsigned short*)(ws);            // 8 MB (Wq|Wk|Wv|Wo)
  unsigned short* xn = (unsigned short*)(ws + 8 * MB);    // 8 MB (aliased: outw)
  unsigned short* qq = (unsigned short*)(ws + 16 * MB);   // 8 MB (bh,S,64)
  unsigned short* kk80 = (unsigned short*)(ws + 24 * MB); // 10 MB (bh,S,80)
  unsigned short* vT = (unsigned short*)(ws + 34 * MB);   // 8 MB (bh,64,S)
  float* cosP = (float*)(ws + 42 * MB);                   // 16 KB
  float* sinP = (float*)(ws + 42 * MB + 16 * 1024);       // 16 KB
  float* Opart = (float*)(ws + 43 * MB);                  // 32 MB ([js][bh][s][d] f32)
  float* lpart = (float*)(ws + 75 * MB);                  // 512 KB ([js][bh][s])
  float* earray = (float*)(ws + 76 * MB);                 // 16 KB (per-token energy)
  unsigned short* outw = xn;  // attn/combine run after qkv consumed xn

  float* y = (float*)d_out;
  float* energy = y + (out_size - 1);

  prep_ln_kernel<<<8192, 256, 0, stream>>>(Wq, Wk, Wv, Wo, wbf, x, Wp, gamma,
                                           beta, xn, cosP, sinP, kk80);
  qkv_gemm_kernel<<<768, 256, 0, stream>>>(xn, wbf, qq, kk80, vT);
  attn_kernel<<<2048, 128, 0, stream>>>(qq, kk80, vT, cosP, sinP, lam, Opart,
                                        lpart);
  combine_kernel<<<M_TOK, 256, 0, stream>>>(Opart, lpart, cosP, sinP, carrier,
                                            outw, earray);
  out_gemm_kernel<<<512, 256, 0, stream>>>(outw, wbf + 3 * D_MODEL * D_MODEL,
                                           x, earray, y, energy);
}

// Round 12
// 208.403 us; speedup vs baseline: 1.8355x; 1.0156x over previous
//
#include <hip/hip_runtime.h>
#include <hip/hip_bf16.h>

#define S_LEN 2048
#define D_MODEL 1024
#define NH 16
#define DH 64
#define M_TOK 4096  // B*S
#define DK 80       // K' row stride: 64 d + cos,sin + pad (cols 72..79 unused)
#define JS 2        // KV splits (fixed-max softmax -> linear combine kernel)

typedef __attribute__((ext_vector_type(8))) short bf16x8;
typedef __attribute__((ext_vector_type(4))) float f32x4;
typedef __attribute__((ext_vector_type(16))) float f32x16;

#define LOG2E 1.4426950408889634f

__device__ __forceinline__ unsigned short f2bf(float f) {
  unsigned u = __float_as_uint(f);
  u += 0x7FFF + ((u >> 16) & 1);  // RNE
  return (unsigned short)(u >> 16);
}

// raw v_exp_f32 (2^x). Scores bounded |x| << 126 here, so identical numerics
// to exp2f's OCML wrapper minus its range-reduction VALU ops.
__device__ __forceinline__ float fexp2(float x) {
#if __has_builtin(__builtin_amdgcn_exp2f)
  return __builtin_amdgcn_exp2f(x);
#else
  float r;
  asm("v_exp_f32 %0, %1" : "=v"(r) : "v"(x));
  return r;
#endif
}

// async 16B global->LDS (LDS dst must be wave-uniform base + lane*16)
__device__ __forceinline__ void gl16(const void* g, void* l) {
  __builtin_amdgcn_global_load_lds(
      (const __attribute__((address_space(1))) unsigned int*)g,
      (__attribute__((address_space(3))) unsigned int*)l, 16, 0, 0);
}

// in-place lane swap: a.hi-lanes <-> b.lo-lanes
__device__ __forceinline__ void pl32swap(unsigned int& a, unsigned int& b) {
  asm volatile("v_permlane32_swap_b32 %0, %1" : "+v"(a), "+v"(b));
}

__device__ __forceinline__ float block_sum(float v, float* sm) {
#pragma unroll
  for (int o = 32; o > 0; o >>= 1) v += __shfl_xor(v, o, 64);
  int w = threadIdx.x >> 6;
  __syncthreads();
  if ((threadIdx.x & 63) == 0) sm[w] = v;
  __syncthreads();
  return sm[0] + sm[1] + sm[2] + sm[3];
}

// ---------------- kernel 1: FUSED weight-cast + LayerNorm/phase ---------------
// blocks [0,4096): cast Wq|Wk|Wv|Wo to bf16.  blocks [4096,8192): LN + phase.
__global__ __launch_bounds__(256) void prep_ln_kernel(
    const float* __restrict__ Wq, const float* __restrict__ Wk,
    const float* __restrict__ Wv, const float* __restrict__ Wo,
    unsigned short* __restrict__ wbf, const float* __restrict__ x,
    const float* __restrict__ Wp, const float* __restrict__ gamma,
    const float* __restrict__ beta, unsigned short* __restrict__ xn,
    float* __restrict__ cosP, float* __restrict__ sinP,
    unsigned short* __restrict__ kk80) {
  __shared__ float sm[4];
  int bid = blockIdx.x;
  int tid = threadIdx.x;
  if (bid < 4096) {
    int idx = (bid * 256 + tid) * 4;
    int wsel = idx >> 20;
    const float* s = (wsel == 0) ? Wq : (wsel == 1) ? Wk : (wsel == 2) ? Wv : Wo;
    int off = idx & 1048575;
    float4 v = *(const float4*)(s + off);
    ushort4 p;
    p.x = f2bf(v.x); p.y = f2bf(v.y); p.z = f2bf(v.z); p.w = f2bf(v.w);
    *(ushort4*)(wbf + idx) = p;
    return;
  }
  int row = bid - 4096;
  float4 v = ((const float4*)(x + (size_t)row * D_MODEL))[tid];
  float mu = block_sum(v.x + v.y + v.z + v.w, sm) * (1.0f / D_MODEL);
  float d0 = v.x - mu, d1 = v.y - mu, d2 = v.z - mu, d3 = v.w - mu;
  float var = block_sum(d0 * d0 + d1 * d1 + d2 * d2 + d3 * d3, sm) * (1.0f / D_MODEL);
  float rinv = rsqrtf(var + 1e-5f);
  float4 g = ((const float4*)gamma)[tid];
  float4 be = ((const float4*)beta)[tid];
  float n0 = d0 * rinv * g.x + be.x;
  float n1 = d1 * rinv * g.y + be.y;
  float n2 = d2 * rinv * g.z + be.z;
  float n3 = d3 * rinv * g.w + be.w;
  ushort4 p;
  p.x = f2bf(n0); p.y = f2bf(n1); p.z = f2bf(n2); p.w = f2bf(n3);
  ((ushort4*)(xn + (size_t)row * D_MODEL))[tid] = p;
  float4 wp = ((const float4*)Wp)[tid];
  float ph = block_sum(n0 * wp.x + n1 * wp.y + n2 * wp.z + n3 * wp.w, sm);
  if (tid == 0) {
    cosP[row] = cosf(ph);
    sinP[row] = sinf(ph);
  }
  if (tid < 16) {
    float cp = cosf(ph), sp = sinf(ph);
    unsigned int w0 = (unsigned int)f2bf(cp) | ((unsigned int)f2bf(sp) << 16);
    int b_ = row >> 11, s_ = row & (S_LEN - 1);
    *(int4*)(kk80 + ((size_t)((b_ * NH + tid) * S_LEN + s_)) * DK + 64) =
        make_int4((int)w0, 0, 0, 0);
  }
}

// ---------------- kernel 3: merged QKV GEMM (128x128, BK=64, XCD-swizzled) ----
__global__ __launch_bounds__(256, 3) void qkv_gemm_kernel(
    const unsigned short* __restrict__ xn, const unsigned short* __restrict__ wbf,
    unsigned short* __restrict__ q, unsigned short* __restrict__ kk80,
    unsigned short* __restrict__ vT) {
  __shared__ __align__(16) unsigned short As[128 * 64];
  __shared__ __align__(16) unsigned short Bs[128 * 64];
  int bid = blockIdx.x;
  bool vmode = bid >= 512;
  const unsigned short* Ap;
  const unsigned short* Bp;
  int m0, n0;
  if (!vmode) {
    int xcd = bid & 7, slot = bid >> 3;       // slot in [0,64)
    int n = slot & 15, mh = slot >> 4;        // mh in [0,4)
    int m = (mh << 3) | xcd;                  // m in [0,32)
    m0 = m * 128;                             // token tile
    n0 = n * 128;                             // e tile over stacked Wq|Wk
    Ap = xn; Bp = wbf;
  } else {
    int b2 = bid - 512;
    int xcd = b2 & 7, slot = b2 >> 3;         // slot in [0,32)
    int m = slot & 7, nh = slot >> 3;         // nh in [0,4)
    int n = (nh << 3) | xcd;                  // n in [0,32)
    m0 = m * 128;                             // Wv row tile (e)
    n0 = n * 128;                             // token tile
    Ap = wbf + 2 * D_MODEL * D_MODEL; Bp = xn;
  }
  int tid = threadIdx.x;
  int wave = tid >> 6, lane = tid & 63, quad = lane >> 4, l15 = lane & 15;
  int wm = (wave & 1) * 64, wn = (wave >> 1) * 64;
  f32x4 acc[4][4];
#pragma unroll
  for (int r = 0; r < 4; ++r)
#pragma unroll
    for (int c = 0; c < 4; ++c) acc[r][c] = (f32x4){0.f, 0.f, 0.f, 0.f};

  for (int k0 = 0; k0 < D_MODEL; k0 += 64) {
    __syncthreads();
#pragma unroll
    for (int t = 0; t < 4; ++t) {
      int c = t * 256 + tid;
      int r = c >> 3, p = c & 7;
      int g = p ^ (r & 7);
      gl16(&Ap[(size_t)(m0 + r) * D_MODEL + k0 + g * 8], &As[c * 8]);
      gl16(&Bp[(size_t)(n0 + r) * D_MODEL + k0 + g * 8], &Bs[c * 8]);
    }
    __syncthreads();
    bf16x8 af[4][2], bfr[4][2];
#pragma unroll
    for (int r = 0; r < 4; ++r) {
      int R = wm + r * 16 + l15;
#pragma unroll
      for (int h = 0; h < 2; ++h)
        af[r][h] = *(const bf16x8*)&As[R * 64 + ((h * 4 + quad) ^ (R & 7)) * 8];
    }
#pragma unroll
    for (int c = 0; c < 4; ++c) {
      int R = wn + c * 16 + l15;
#pragma unroll
      for (int h = 0; h < 2; ++h)
        bfr[c][h] = *(const bf16x8*)&Bs[R * 64 + ((h * 4 + quad) ^ (R & 7)) * 8];
    }
#pragma unroll
    for (int h = 0; h < 2; ++h)
#pragma unroll
      for (int r = 0; r < 4; ++r)
#pragma unroll
        for (int c = 0; c < 4; ++c)
          acc[r][c] = __builtin_amdgcn_mfma_f32_16x16x32_bf16(af[r][h], bfr[c][h], acc[r][c], 0, 0, 0);
  }
#pragma unroll
  for (int r = 0; r < 4; ++r) {
#pragma unroll
    for (int c = 0; c < 4; ++c) {
#pragma unroll
      for (int rr = 0; rr < 4; ++rr) {
        if (vmode) {
          int e = m0 + wm + r * 16 + quad * 4 + rr;
          int tok = n0 + wn + c * 16 + l15;
          int hh = e >> 6, d = e & 63;
          int bb = tok >> 11, ss = tok & (S_LEN - 1);
          vT[(((size_t)(bb * NH + hh)) * DH + d) * S_LEN + ss] = f2bf(acc[r][c][rr]);
        } else {
          int tok = m0 + wm + r * 16 + quad * 4 + rr;
          int n = n0 + wn + c * 16 + l15;
          int e = n & 1023;
          int hh = e >> 6, d = e & 63;
          int bb = tok >> 11, ss = tok & (S_LEN - 1);
          if ((n0 >> 10) == 0) {
            q[(((size_t)(bb * NH + hh)) * S_LEN + ss) * DH + d] =
                f2bf(acc[r][c][rr] * (0.125f * LOG2E));
          } else {
            kk80[(((size_t)(bb * NH + hh)) * S_LEN + ss) * DK + d] = f2bf(acc[r][c][rr]);
          }
        }
      }
    }
  }
}

// ---------------- kernel 4: flash attention (R9/R11 proven) -------------------
__global__ __launch_bounds__(128, 4) void attn_kernel(
    const unsigned short* __restrict__ q, const unsigned short* __restrict__ kk80,
    const unsigned short* __restrict__ vT, const float* __restrict__ cosP,
    const float* __restrict__ sinP, const float* __restrict__ lamp,
    float* __restrict__ Opart, float* __restrict__ lpart) {
  __shared__ __align__(16) unsigned short Ks[64 * 72];   // natural, 9 chunks/row
  __shared__ __align__(16) unsigned short Vs[512 * 8];   // Vs[d][j], XOR-swizzled
  int bid = blockIdx.x;              // swizzled decode
  int slot = bid >> 3;
  int g = ((slot >> 5) << 3) | (bid & 7);  // group = h + 16*(b + 2*js)
  int qt = slot & 31;
  int h = g & 15;
  int b = (g >> 4) & 1;
  int js = g >> 5;
  int bh = b * NH + h;
  int tid = threadIdx.x, wave = tid >> 6, lane = tid & 63;
  int half = lane >> 5, l31 = lane & 31;

  const unsigned short* kb = kk80 + (size_t)bh * S_LEN * DK;
  const unsigned short* vb = vT + (size_t)bh * DH * S_LEN;
  int qrow = qt * 64 + wave * 32 + l31;

  // Q fragments: B[n=i][k], d-blocks 0..3 from global, block 4 = phase cols
  bf16x8 bQ[5];
  {
    const unsigned short* qp = q + ((size_t)bh * S_LEN + qrow) * DH;
#pragma unroll
    for (int db = 0; db < 4; ++db)
      bQ[db] = *(const bf16x8*)(qp + db * 16 + half * 8);
    bf16x8 z8 = {0, 0, 0, 0, 0, 0, 0, 0};
    if (half == 0) {
      float hl2 = 0.5f * lamp[0] * LOG2E;
      z8[0] = (short)f2bf(hl2 * cosP[b * S_LEN + qrow]);
      z8[1] = (short)f2bf(hl2 * sinP[b * S_LEN + qrow]);
    }
    bQ[4] = z8;
  }

  // tile-invariant staging offsets (hoisted out of j-loop)
  unsigned int cc0 = tid, cc1 = tid + 128, cc2 = tid + 256, cc3 = tid + 384,
               cc4 = tid + 512;
  unsigned int kr0 = cc0 / 9u, kr1 = cc1 / 9u, kr2 = cc2 / 9u, kr3 = cc3 / 9u,
               kr4 = cc4 / 9u;
  unsigned int ko0 = kr0 * DK + (cc0 - kr0 * 9u) * 8;
  unsigned int ko1 = kr1 * DK + (cc1 - kr1 * 9u) * 8;
  unsigned int ko2 = kr2 * DK + (cc2 - kr2 * 9u) * 8;
  unsigned int ko3 = kr3 * DK + (cc3 - kr3 * 9u) * 8;
  unsigned int ko4 = kr4 * DK + (cc4 - kr4 * 9u) * 8;
  unsigned short* kl0 = (unsigned short*)Ks + cc0 * 8;
  unsigned short* kl1 = (unsigned short*)Ks + cc1 * 8;
  unsigned short* kl2 = (unsigned short*)Ks + cc2 * 8;
  unsigned short* kl3 = (unsigned short*)Ks + cc3 * 8;
  unsigned short* kl4 = (unsigned short*)Ks + cc4 * 8;
  unsigned int vr0 = cc0 >> 3, vr1 = cc1 >> 3, vr2 = cc2 >> 3, vr3 = cc3 >> 3;
  unsigned int vo0 = vr0 * S_LEN + ((cc0 & 7) ^ (vr0 & 7)) * 8;
  unsigned int vo1 = vr1 * S_LEN + ((cc1 & 7) ^ (vr1 & 7)) * 8;
  unsigned int vo2 = vr2 * S_LEN + ((cc2 & 7) ^ (vr2 & 7)) * 8;
  unsigned int vo3 = vr3 * S_LEN + ((cc3 & 7) ^ (vr3 & 7)) * 8;
  unsigned short* vl0 = (unsigned short*)Vs + cc0 * 8;
  unsigned short* vl1 = (unsigned short*)Vs + cc1 * 8;
  unsigned short* vl2 = (unsigned short*)Vs + cc2 * 8;
  unsigned short* vl3 = (unsigned short*)Vs + cc3 * 8;

  const unsigned short* kbt = kb + (size_t)(js * (S_LEN / JS)) * DK;
  const unsigned short* vbt = vb + js * (S_LEN / JS);

  f32x16 O0 = {}, O1 = {};
  float2 l2 = {0.f, 0.f};

  for (int jt = 0; jt < S_LEN / (64 * JS); ++jt) {
    __syncthreads();
    gl16(kbt + ko0, kl0);
    gl16(kbt + ko1, kl1);
    gl16(kbt + ko2, kl2);
    gl16(kbt + ko3, kl3);
    if (tid < 64) gl16(kbt + ko4, kl4);
    gl16(vbt + vo0, vl0);
    gl16(vbt + vo1, vl1);
    gl16(vbt + vo2, vl2);
    gl16(vbt + vo3, vl3);
    kbt += 64 * DK;
    vbt += 64;
    __syncthreads();

    // S^T: A = K' (m=j), B = Q' (n=i); 2 j-subtiles x 5 d-blocks
    f32x16 Sf[2];
#pragma unroll
    for (int sj = 0; sj < 2; ++sj) {
      Sf[sj] = (f32x16){};
      int r = sj * 32 + l31;
      __builtin_amdgcn_s_setprio(1);
#pragma unroll
      for (int db = 0; db < 5; ++db) {
        int p = (db < 4) ? (db * 2 + half) : 8;  // db=4,half=1: don't-care (B zero)
        bf16x8 aK = *(const bf16x8*)((const unsigned short*)Ks + (r * 9 + p) * 8);
        Sf[sj] = __builtin_amdgcn_mfma_f32_32x32x16_bf16(aK, bQ[db], Sf[sj], 0, 0, 0);
      }
      __builtin_amdgcn_s_setprio(0);
    }

    // softmax (raw v_exp_f32) + P->A-frag in-register, then PV
#pragma unroll
    for (int sj = 0; sj < 2; ++sj) {
      unsigned int w[8];
#pragma unroll
      for (int rr = 0; rr < 8; ++rr) {
        float e0 = fexp2(Sf[sj][rr * 2 + 0]);
        float e1 = fexp2(Sf[sj][rr * 2 + 1]);
        l2.x += e0;
        l2.y += e1;
        __hip_bfloat162 pk2 = __float22bfloat162_rn(float2{e0, e1});
        w[rr] = *(unsigned int*)&pk2;
      }
#pragma unroll
      for (int u = 0; u < 2; ++u) {
        unsigned int a0 = w[u * 4 + 0], a1 = w[u * 4 + 1];
        unsigned int b0 = w[u * 4 + 2], b1 = w[u * 4 + 3];
        pl32swap(a0, b0);
        pl32swap(a1, b1);
        union { unsigned int u4[4]; bf16x8 v; } cvt;
        cvt.u4[0] = a0; cvt.u4[1] = a1; cvt.u4[2] = b0; cvt.u4[3] = b1;
        int jb = sj * 2 + u;
        __builtin_amdgcn_s_setprio(1);
        {
          int rv = l31;
          int p = (jb * 2 + half) ^ (rv & 7);
          bf16x8 bV = *(const bf16x8*)((const unsigned short*)Vs + (rv * 8 + p) * 8);
          O0 = __builtin_amdgcn_mfma_f32_32x32x16_bf16(cvt.v, bV, O0, 0, 0, 0);
        }
        {
          int rv = 32 + l31;
          int p = (jb * 2 + half) ^ (rv & 7);
          bf16x8 bV = *(const bf16x8*)((const unsigned short*)Vs + (rv * 8 + p) * 8);
          O1 = __builtin_amdgcn_mfma_f32_32x32x16_bf16(cvt.v, bV, O1, 0, 0, 0);
        }
        __builtin_amdgcn_s_setprio(0);
      }
    }
  }

  // epilogue: complete per-row sums, store f32 partials (no gate/normalize here)
  float l_i = l2.x + l2.y;
  l_i += __shfl_xor(l_i, 32, 64);
  size_t obase = (size_t)(js * 2 * NH + bh) * S_LEN;  // [js][bh] plane
#pragma unroll
  for (int reg = 0; reg < 16; ++reg) {
    int ir = (reg & 3) + 8 * (reg >> 2) + 4 * half;
    int srow = qt * 64 + wave * 32 + ir;
    Opart[((size_t)(obase + srow)) * DH + l31] = O0[reg];
    Opart[((size_t)(obase + srow)) * DH + 32 + l31] = O1[reg];
  }
  if (half == 0) lpart[obase + qt * 64 + wave * 32 + l31] = l_i;
}

// ---------------- kernel 4b: combine, XCD-LOCAL grid --------------------------
// attn pins head h's partials to XCD (h&7) (bid%8 round-robin, confirmed by
// R9's 5x FETCH drop). Old token-major combine read all 16 heads per block ->
// cross-XCD L2 misses + writebacks. New grid: block = (bh, 64-token range),
// placed on XCD (h&7) via the same bid&7 key -> Opart reads are local-L2 hits.
// Each thread: one token, 16 d-elems (4x float4 per plane), 2x 16B outw store.
__global__ __launch_bounds__(256) void combine_kernel(
    const float* __restrict__ Opart, const float* __restrict__ lpart,
    const float* __restrict__ cosP, const float* __restrict__ sinP,
    const float* __restrict__ carrier, unsigned short* __restrict__ outw,
    float* __restrict__ earray) {
  __shared__ float sm[4];
  int bid = blockIdx.x;  // 1024 blocks
  int xcd = bid & 7, slot = bid >> 3;   // slot in [0,128)
  int hi = slot & 1, b = (slot >> 1) & 1, sb = slot >> 2;  // sb in [0,32)
  int h = xcd + 8 * hi;
  int bh = b * NH + h;
  int t = threadIdx.x;
  int s = sb * 64 + (t >> 2);
  int d0 = (t & 3) * 16;
  const size_t plane = (size_t)2 * NH * S_LEN;  // js stride in rows
  size_t row0 = (size_t)bh * S_LEN + s;
  const float* p0 = Opart + row0 * DH + d0;
  const float* p1 = Opart + (plane + row0) * DH + d0;
  float l = lpart[row0] + lpart[plane + row0];
  float ch = cosf(carrier[h]), sh = sinf(carrier[h]);
  int tok = b * S_LEN + s;
  float cp = cosP[tok], sp = sinP[tok];
  float gate = 0.5f + 0.5f * (cp * ch + sp * sh);
  float gl = gate / l;
  unsigned short obuf[16];
  float esum = 0.f;
#pragma unroll
  for (int i = 0; i < 4; ++i) {
    float4 a0 = *(const float4*)(p0 + i * 4);
    float4 a1 = *(const float4*)(p1 + i * 4);
    float v0 = (a0.x + a1.x) * gl, v1 = (a0.y + a1.y) * gl;
    float v2 = (a0.z + a1.z) * gl, v3 = (a0.w + a1.w) * gl;
    esum += fabsf(v0) + fabsf(v1) + fabsf(v2) + fabsf(v3);
    obuf[i * 4 + 0] = f2bf(v0); obuf[i * 4 + 1] = f2bf(v1);
    obuf[i * 4 + 2] = f2bf(v2); obuf[i * 4 + 3] = f2bf(v3);
  }
  unsigned short* od = outw + (size_t)tok * D_MODEL + h * DH + d0;
  *(int4*)(od) = *(int4*)(obuf);
  *(int4*)(od + 8) = *(int4*)(obuf + 8);
  float tot = block_sum(esum, sm);
  if (t == 0) earray[bid] = tot;  // per-block partial, no atomic
}

// ---------------- kernel 5: output projection + residual (128x64, 2 blk/CU) --
// 1-D swizzled grid: 16 n-blocks sharing an outw token-panel cluster per XCD.
// Block 0 folds the 1024-entry energy reduction (plain store).
__global__ __launch_bounds__(256, 3) void out_gemm_kernel(
    const unsigned short* __restrict__ A, const unsigned short* __restrict__ Wo,
    const float* __restrict__ x, const float* __restrict__ earray,
    float* __restrict__ y, float* __restrict__ energy) {
  __shared__ __align__(16) unsigned short As[128 * 64];
  __shared__ __align__(16) unsigned short Bs[64 * 64];
  __shared__ float sm[4];
  int tid = threadIdx.x;
  int bid = blockIdx.x;  // 512 blocks
  if (bid == 0) {
    float v = earray[tid] + earray[tid + 256] + earray[tid + 512] + earray[tid + 768];
    float tot = block_sum(v, sm);
    if (tid == 0) *energy = tot;
  }
  int xcd = bid & 7, slot = bid >> 3;   // slot in [0,64)
  int n = slot & 15, mh = slot >> 4;    // mh in [0,4)
  int m = (mh << 3) | xcd;              // m in [0,32)
  int m0 = m * 128, n0 = n * 64;
  int wave = tid >> 6, lane = tid & 63, quad = lane >> 4, l15 = lane & 15;
  int wm = (wave & 1) * 64, wn = (wave >> 1) * 32;
  f32x4 acc[4][2];
#pragma unroll
  for (int r = 0; r < 4; ++r)
#pragma unroll
    for (int c = 0; c < 2; ++c) acc[r][c] = (f32x4){0.f, 0.f, 0.f, 0.f};

  for (int k0 = 0; k0 < D_MODEL; k0 += 64) {
    __syncthreads();
#pragma unroll
    for (int t = 0; t < 4; ++t) {
      int c = t * 256 + tid;
      int r = c >> 3, p = c & 7;
      int qc = p ^ (r & 7);
      gl16(&A[(size_t)(m0 + r) * D_MODEL + k0 + qc * 8], &As[c * 8]);
    }
#pragma unroll
    for (int t = 0; t < 2; ++t) {
      int c = t * 256 + tid;
      int r = c >> 3, p = c & 7;
      int qc = p ^ (r & 7);
      gl16(&Wo[(size_t)(n0 + r) * D_MODEL + k0 + qc * 8], &Bs[c * 8]);
    }
    __syncthreads();
    bf16x8 af[4][2], bfr[2][2];
#pragma unroll
    for (int r = 0; r < 4; ++r) {
      int R = wm + r * 16 + l15;
#pragma unroll
      for (int h = 0; h < 2; ++h)
        af[r][h] = *(const bf16x8*)&As[R * 64 + ((h * 4 + quad) ^ (R & 7)) * 8];
    }
#pragma unroll
    for (int c = 0; c < 2; ++c) {
      int R = wn + c * 16 + l15;
#pragma unroll
      for (int h = 0; h < 2; ++h)
        bfr[c][h] = *(const bf16x8*)&Bs[R * 64 + ((h * 4 + quad) ^ (R & 7)) * 8];
    }
#pragma unroll
    for (int h = 0; h < 2; ++h)
#pragma unroll
      for (int r = 0; r < 4; ++r)
#pragma unroll
        for (int c = 0; c < 2; ++c)
          acc[r][c] = __builtin_amdgcn_mfma_f32_16x16x32_bf16(af[r][h], bfr[c][h], acc[r][c], 0, 0, 0);
  }
#pragma unroll
  for (int r = 0; r < 4; ++r) {
#pragma unroll
    for (int c = 0; c < 2; ++c) {
      int dcol = n0 + wn + c * 16 + l15;
#pragma unroll
      for (int rr = 0; rr < 4; ++rr) {
        int tok = m0 + wm + r * 16 + quad * 4 + rr;
        size_t idx = (size_t)tok * D_MODEL + dcol;
        y[idx] = x[idx] + acc[r][c][rr];
      }
    }
  }
}

extern "C" void kernel_launch(void* const* d_in, const int* in_sizes, int n_in,
                              void* d_out, int out_size, void* d_ws, size_t ws_size,
                              hipStream_t stream) {
  const float* x = (const float*)d_in[0];
  const float* Wq = (const float*)d_in[1];
  const float* Wk = (const float*)d_in[2];
  const float* Wv = (const float*)d_in[3];
  const float* Wo = (const float*)d_in[4];
  const float* Wp = (const float*)d_in[5];
  const float* gamma = (const float*)d_in[6];
  const float* beta = (const float*)d_in[7];
  const float* carrier = (const float*)d_in[8];
  const float* lam = (const float*)d_in[9];

  char* ws = (char*)d_ws;
  const size_t MB = 1024 * 1024;
  unsigned short* wbf = (unsigned short*)(ws);            // 8 MB (Wq|Wk|Wv|Wo)
  unsigned short* xn = (unsigned short*)(ws + 8 * MB);    // 8 MB (aliased: outw)
  unsigned short* qq = (unsigned short*)(ws + 16 * MB);   // 8 MB (bh,S,64)
  unsigned short* kk80 = (unsigned short*)(ws + 24 * MB); // 10 MB (bh,S,80)
  unsigned short* vT = (unsigned short*)(ws + 34 * MB);   // 8 MB (bh,64,S)
  float* cosP = (float*)(ws + 42 * MB);                   // 16 KB
  float* sinP = (float*)(ws + 42 * MB + 16 * 1024);       // 16 KB
  float* Opart = (float*)(ws + 43 * MB);                  // 32 MB ([js][bh][s][d] f32)
  float* lpart = (float*)(ws + 75 * MB);                  // 512 KB ([js][bh][s])
  float* earray = (float*)(ws + 76 * MB);                 // 4 KB (per-block energy)
  unsigned short* outw = xn;  // attn/combine run after qkv consumed xn

  float* y = (float*)d_out;
  float* energy = y + (out_size - 1);

  prep_ln_kernel<<<8192, 256, 0, stream>>>(Wq, Wk, Wv, Wo, wbf, x, Wp, gamma,
                                           beta, xn, cosP, sinP, kk80);
  qkv_gemm_kernel<<<768, 256, 0, stream>>>(xn, wbf, qq, kk80, vT);
  attn_kernel<<<2048, 128, 0, stream>>>(qq, kk80, vT, cosP, sinP, lam, Opart,
                                        lpart);
  combine_kernel<<<1024, 256, 0, stream>>>(Opart, lpart, cosP, sinP, carrier,
                                           outw, earray);
  out_gemm_kernel<<<512, 256, 0, stream>>>(outw, wbf + 3 * D_MODEL * D_MODEL,
                                           x, earray, y, energy);
}